// Round 7
// baseline (799.349 us; speedup 1.0000x reference)
//
#include <hip/hip_runtime.h>
#include <hip/hip_bf16.h>

#define S 4096
#define DM 768
#define NH 12
#define DK 64
#define KSPLIT 2
#define KHALF (S / KSPLIT)

typedef __bf16 bf16x8 __attribute__((ext_vector_type(8)));
typedef __bf16 bf16x4 __attribute__((ext_vector_type(4)));
typedef float f32x4 __attribute__((ext_vector_type(4)));
using bf16 = __hip_bfloat16;

__device__ inline bf16x8 load_frag(const bf16* p) {
    return *reinterpret_cast<const bf16x8*>(p);
}

// Detect input dtype (f32 vs bf16) from bit patterns; flag=1 -> f32.
__global__ void k_detect(const unsigned int* __restrict__ q, int* __restrict__ flag) {
    const int lane = threadIdx.x;  // 64 threads
    int cnt = 0;
    for (int i = lane; i < 1024; i += 64) {
        const unsigned int w = q[i];
        const int e = (w >> 7) & 0xFF;
        if (e >= 192 || (e > 0 && e < 64)) cnt++;
    }
    for (int m = 1; m < 64; m <<= 1) cnt += __shfl_xor(cnt, m, 64);
    if (lane == 0) flag[0] = (cnt > 64) ? 1 : 0;
}

__device__ inline void cast_body(const void* src, bf16* dst, int n, int isf32) {
    const int stride = gridDim.x * 256 * 8;
    for (int i = (blockIdx.x * 256 + threadIdx.x) * 8; i < n; i += stride) {
        if (isf32) {
            const float* s = (const float*)src + i;
            float4 a = *(const float4*)(s);
            float4 b = *(const float4*)(s + 4);
            bf16x8 o;
            o[0] = (__bf16)a.x; o[1] = (__bf16)a.y; o[2] = (__bf16)a.z; o[3] = (__bf16)a.w;
            o[4] = (__bf16)b.x; o[5] = (__bf16)b.y; o[6] = (__bf16)b.z; o[7] = (__bf16)b.w;
            *reinterpret_cast<bf16x8*>(dst + i) = o;
        } else {
            *reinterpret_cast<bf16x8*>(dst + i) =
                *reinterpret_cast<const bf16x8*>((const __bf16*)src + i);
        }
    }
}

__global__ __launch_bounds__(256) void k_cast3(
    const void* s0, const void* s1, const void* s2,
    bf16* d0, bf16* d1, bf16* d2, int n, const int* __restrict__ flag) {
    const int t = blockIdx.y;
    const void* s = (t == 0) ? s0 : (t == 1) ? s1 : s2;
    bf16* d = (t == 0) ? d0 : (t == 1) ? d1 : d2;
    cast_body(s, d, n, flag[0]);
}

__global__ __launch_bounds__(256) void k_cast4(
    const void* s0, const void* s1, const void* s2, const void* s3,
    bf16* d0, bf16* d1, bf16* d2, bf16* d3, int n, const int* __restrict__ flag) {
    const int t = blockIdx.y;
    const void* s = (t == 0) ? s0 : (t == 1) ? s1 : (t == 2) ? s2 : s3;
    bf16* d = (t == 0) ? d0 : (t == 1) ? d1 : (t == 2) ? d2 : d3;
    cast_body(s, d, n, flag[0]);
}

// x @ W^T + b. mode 0/1: head-split [H][S][DK]; mode 2: transposed [DM][S];
// mode 3: row-major [S][DM], dtype per flag.   (verbatim from R5, verified)
__global__ __launch_bounds__(256) void k_proj(
    const bf16* __restrict__ X, const bf16* __restrict__ W,
    const bf16* __restrict__ bias, void* __restrict__ dstv, int mode,
    const int* __restrict__ flag)
{
    const int isf32 = flag[0];
    const int lane = threadIdx.x & 63;
    const int w    = threadIdx.x >> 6;
    const int lr   = lane & 15, lg = lane >> 4;
    const int rbase = blockIdx.x * 64 + w * 16;
    const int nbase = blockIdx.y * 64;

    f32x4 acc[4] = {};
    const bf16* xrow = X + (size_t)(rbase + lr) * DM + lg * 8;
    for (int kk = 0; kk < DM; kk += 32) {
        bf16x8 a = load_frag(xrow + kk);
#pragma unroll
        for (int nt = 0; nt < 4; ++nt) {
            bf16x8 b = load_frag(W + (size_t)(nbase + nt * 16 + lr) * DM + kk + lg * 8);
            acc[nt] = __builtin_amdgcn_mfma_f32_16x16x32_bf16(a, b, acc[nt], 0, 0, 0);
        }
    }
#pragma unroll
    for (int nt = 0; nt < 4; ++nt) {
        const int col = nbase + nt * 16 + lr;
        const float bv = __bfloat162float(bias[col]);
#pragma unroll
        for (int r = 0; r < 4; ++r) {
            const int row = rbase + lg * 4 + r;
            const float v = acc[nt][r] + bv;
            if (mode == 3) {
                const size_t off = (size_t)row * DM + col;
                if (isf32) ((float*)dstv)[off] = v;
                else       ((bf16*)dstv)[off] = __float2bfloat16(v);
            } else {
                size_t off;
                if (mode == 2) off = (size_t)col * S + row;
                else           off = (size_t)(col >> 6) * (S * DK) + (size_t)row * DK + (col & 63);
                ((bf16*)dstv)[off] = __float2bfloat16(v);
            }
        }
    }
}

// Partial row sums of exp(scores/8) over this block's k-half. (verbatim R5)
__global__ __launch_bounds__(256) void k_rowsum(
    const bf16* __restrict__ qh, const bf16* __restrict__ kh,
    float* __restrict__ rs)
{
    const int lane = threadIdx.x & 63;
    const int w    = threadIdx.x >> 6;
    const int lr   = lane & 15, lg = lane >> 4;
    const int h    = blockIdx.y;
    const int half = blockIdx.z;
    const int q0   = blockIdx.x * 64 + w * 16;

    const bf16* qb = qh + (size_t)h * (S * DK);
    const bf16* kb = kh + (size_t)h * (S * DK);
    const bf16x8 aq0 = load_frag(qb + (size_t)(q0 + lr) * DK + lg * 8);
    const bf16x8 aq1 = load_frag(qb + (size_t)(q0 + lr) * DK + 32 + lg * 8);

    float s = 0.f;
    for (int kp = half * KHALF; kp < half * KHALF + KHALF; kp += 16) {
        bf16x8 b0 = load_frag(kb + (size_t)(kp + lr) * DK + lg * 8);
        bf16x8 b1 = load_frag(kb + (size_t)(kp + lr) * DK + 32 + lg * 8);
        f32x4 d = {};
        d = __builtin_amdgcn_mfma_f32_16x16x32_bf16(b0, aq0, d, 0, 0, 0);
        d = __builtin_amdgcn_mfma_f32_16x16x32_bf16(b1, aq1, d, 0, 0, 0);
        s += __expf(d[0] * 0.125f) + __expf(d[1] * 0.125f) +
             __expf(d[2] * 0.125f) + __expf(d[3] * 0.125f);
    }
    s += __shfl_xor(s, 16, 64);
    s += __shfl_xor(s, 32, 64);
    if (lane < 16)
        rs[(size_t)half * NH * S + (size_t)h * S + q0 + lr] = s;
}

// R5 skeleton (wave-private 16-row tiles), with one change: stage TWO 64-k
// tiles of bf16 P (stride 136 = 16B-aligned rows), flush every 2 tiles with
// 512B-contiguous nontemporal stores (lanes 0-31 / 32-63 = two full rows).
__global__ __launch_bounds__(256) void k_attn(
    const bf16* __restrict__ qh, const bf16* __restrict__ kh,
    const bf16* __restrict__ vt, const float* __restrict__ rs,
    void* __restrict__ doutv, bf16* __restrict__ ctxp,
    const int* __restrict__ flag)
{
    __shared__ __align__(16) bf16 Plds[4][16][136];
    const int isf32 = flag[0];
    const int lane = threadIdx.x & 63;
    const int w    = threadIdx.x >> 6;
    const int lr   = lane & 15, lg = lane >> 4;
    const int h    = blockIdx.y;
    const int half = blockIdx.z;
    const int q0   = blockIdx.x * 64 + w * 16;
    const int k0   = half * KHALF;

    const bf16* qb = qh + (size_t)h * (S * DK);
    const bf16* kb = kh + (size_t)h * (S * DK);
    const bf16* vb = vt + (size_t)h * (S * DK);
    const bf16x8 aq0 = load_frag(qb + (size_t)(q0 + lr) * DK + lg * 8);
    const bf16x8 aq1 = load_frag(qb + (size_t)(q0 + lr) * DK + 32 + lg * 8);

    const float inv_s = 1.0f / (rs[(size_t)h * S + q0 + lr] +
                                rs[(size_t)NH * S + (size_t)h * S + q0 + lr]);

    float* poutF = (float*)doutv + (size_t)S * DM + (size_t)h * S * S;
    bf16*  poutB = (bf16*)doutv  + (size_t)S * DM + (size_t)h * S * S;

    // flush mapping: half-wave -> row parity, lane&31 -> 4-col chunk
    const int fr2 = lane >> 5;          // 0..1
    const int fc2 = (lane & 31) * 4;    // 0..124

    f32x4 acc[4] = {};
    for (int tp = 0; tp < KHALF / 128; ++tp) {   // 16 iterations of 2 tiles
#pragma unroll
        for (int tt = 0; tt < 2; ++tt) {
            const int kt = k0 + tp * 128 + tt * 64;
            const int cb = tt * 64;              // column base in Plds
#pragma unroll
            for (int sub = 0; sub < 4; ++sub) {
                const int kp = kt + sub * 16;
                bf16x8 b0 = load_frag(kb + (size_t)(kp + lr) * DK + lg * 8);
                bf16x8 b1 = load_frag(kb + (size_t)(kp + lr) * DK + 32 + lg * 8);
                f32x4 d = {};
                d = __builtin_amdgcn_mfma_f32_16x16x32_bf16(b0, aq0, d, 0, 0, 0);
                d = __builtin_amdgcn_mfma_f32_16x16x32_bf16(b1, aq1, d, 0, 0, 0);
                bf16x4 pv;
                pv[0] = (__bf16)(__expf(d[0] * 0.125f) * inv_s);
                pv[1] = (__bf16)(__expf(d[1] * 0.125f) * inv_s);
                pv[2] = (__bf16)(__expf(d[2] * 0.125f) * inv_s);
                pv[3] = (__bf16)(__expf(d[3] * 0.125f) * inv_s);
                *reinterpret_cast<bf16x4*>(&Plds[w][lr][cb + sub * 16 + 4 * lg]) = pv;
            }
            // PV on this 64-k tile
            bf16x8 ap0 = *reinterpret_cast<const bf16x8*>(&Plds[w][lr][cb + lg * 8]);
            bf16x8 ap1 = *reinterpret_cast<const bf16x8*>(&Plds[w][lr][cb + 32 + lg * 8]);
#pragma unroll
            for (int dt = 0; dt < 4; ++dt) {
                bf16x8 v0 = load_frag(vb + (size_t)(dt * 16 + lr) * S + kt + lg * 8);
                bf16x8 v1 = load_frag(vb + (size_t)(dt * 16 + lr) * S + kt + 32 + lg * 8);
                acc[dt] = __builtin_amdgcn_mfma_f32_16x16x32_bf16(ap0, v0, acc[dt], 0, 0, 0);
                acc[dt] = __builtin_amdgcn_mfma_f32_16x16x32_bf16(ap1, v1, acc[dt], 0, 0, 0);
            }
        }
        // flush 2 tiles: rows q0..q0+15, cols ktbase..ktbase+127
        const int ktbase = k0 + tp * 128;
        if (isf32) {
#pragma unroll
            for (int j = 0; j < 8; ++j) {
                const int row = 2 * j + fr2;
                bf16x4 x = *reinterpret_cast<const bf16x4*>(&Plds[w][row][fc2]);
                f32x4 o;
                o[0] = (float)x[0]; o[1] = (float)x[1];
                o[2] = (float)x[2]; o[3] = (float)x[3];
                __builtin_nontemporal_store(
                    o, reinterpret_cast<f32x4*>(
                           poutF + (size_t)(q0 + row) * S + ktbase + fc2));
            }
        } else {
#pragma unroll
            for (int j = 0; j < 8; ++j) {
                const int row = 2 * j + fr2;
                bf16x4 x = *reinterpret_cast<const bf16x4*>(&Plds[w][row][fc2]);
                *reinterpret_cast<bf16x4*>(
                    poutB + (size_t)(q0 + row) * S + ktbase + fc2) = x;
            }
        }
        __syncthreads();  // also orders flush-reads vs next tile-pair's stores
    }
    bf16* cp = ctxp + (size_t)half * S * DM;
#pragma unroll
    for (int dt = 0; dt < 4; ++dt)
#pragma unroll
        for (int r = 0; r < 4; ++r)
            cp[(size_t)(q0 + 4 * lg + r) * DM + h * DK + dt * 16 + lr] =
                __float2bfloat16(acc[dt][r]);
}

// ctx = ctxp[0] + ctxp[1] (bf16)
__global__ __launch_bounds__(256) void k_reduce(const bf16* __restrict__ ctxp,
                                               bf16* __restrict__ ctx) {
    const int i = (blockIdx.x * 256 + threadIdx.x) * 8;
    bf16x8 a = *reinterpret_cast<const bf16x8*>(ctxp + i);
    bf16x8 b = *reinterpret_cast<const bf16x8*>(ctxp + (size_t)S * DM + i);
    bf16x8 o;
#pragma unroll
    for (int j = 0; j < 8; ++j) o[j] = (__bf16)((float)a[j] + (float)b[j]);
    *reinterpret_cast<bf16x8*>(ctx + i) = o;
}

extern "C" void kernel_launch(void* const* d_in, const int* in_sizes, int n_in,
                              void* d_out, int out_size, void* d_ws, size_t ws_size,
                              hipStream_t stream) {
    char* wsb = (char*)d_ws;
    int*   flag = (int*)wsb;                                   // 16 B
    float* rs   = (float*)(wsb + 16);                          // 2*NH*S f32
    bf16*  conv = (bf16*)(wsb + 16 + (size_t)2 * NH * S * 4);

    const size_t nQ = (size_t)S * DM, nW = (size_t)DM * DM, nB = DM;
    bf16* Qc  = conv;
    bf16* Kc  = Qc + nQ;
    bf16* Vc  = Kc + nQ;
    bf16* Wqc = Vc + nQ;
    bf16* Wkc = Wqc + nW;
    bf16* Wvc = Wkc + nW;
    bf16* Woc = Wvc + nW;
    bf16* bqc = Woc + nW;
    bf16* bkc = bqc + nB;
    bf16* bvc = bkc + nB;
    bf16* boc = bvc + nB;
    bf16* qh  = boc + nB;
    bf16* kh  = qh + nQ;
    bf16* vt  = kh + nQ;
    // aliases (Qc/Kc/Vc dead after projections):
    bf16* ctxp = Qc;   // 2*nQ bf16 partial ctx
    bf16* ctx  = Vc;   // nQ bf16 summed ctx

    const size_t need = (size_t)((char*)(vt + nQ) - wsb);
    if (ws_size < need) return;

    dim3 blk(256);
    k_detect<<<1, 64, 0, stream>>>((const unsigned int*)d_in[0], flag);

    k_cast3<<<dim3((int)(nQ / 2048), 3), blk, 0, stream>>>(
        d_in[0], d_in[1], d_in[2], Qc, Kc, Vc, (int)nQ, flag);
    k_cast4<<<dim3((int)(nW / 2048), 4), blk, 0, stream>>>(
        d_in[3], d_in[5], d_in[7], d_in[9], Wqc, Wkc, Wvc, Woc, (int)nW, flag);
    k_cast4<<<dim3(1, 4), blk, 0, stream>>>(
        d_in[4], d_in[6], d_in[8], d_in[10], bqc, bkc, bvc, boc, (int)nB, flag);

    k_proj<<<dim3(S / 64, DM / 64), blk, 0, stream>>>(Qc, Wqc, bqc, qh, 0, flag);
    k_proj<<<dim3(S / 64, DM / 64), blk, 0, stream>>>(Kc, Wkc, bkc, kh, 1, flag);
    k_proj<<<dim3(S / 64, DM / 64), blk, 0, stream>>>(Vc, Wvc, bvc, vt, 2, flag);
    k_rowsum<<<dim3(S / 64, NH, KSPLIT), blk, 0, stream>>>(qh, kh, rs);
    k_attn<<<dim3(S / 64, NH, KSPLIT), blk, 0, stream>>>(qh, kh, vt, rs, d_out, ctxp, flag);
    k_reduce<<<dim3((int)(nQ / 8 / 256)), blk, 0, stream>>>(ctxp, ctx);
    k_proj<<<dim3(S / 64, DM / 64), blk, 0, stream>>>(ctx, Woc, boc, d_out, 3, flag);
}

// Round 8
// 629.356 us; speedup vs baseline: 1.2701x; 1.2701x over previous
//
#include <hip/hip_runtime.h>
#include <hip/hip_bf16.h>

#define S 4096
#define DM 768
#define NH 12
#define DK 64
#define KSPLIT 2
#define KHALF (S / KSPLIT)

typedef __bf16 bf16x8 __attribute__((ext_vector_type(8)));
typedef __bf16 bf16x4 __attribute__((ext_vector_type(4)));
typedef float f32x4 __attribute__((ext_vector_type(4)));
using bf16 = __hip_bfloat16;

__device__ inline bf16x8 load_frag(const bf16* p) {
    return *reinterpret_cast<const bf16x8*>(p);
}

// Detect input dtype (f32 vs bf16) from bit patterns; flag=1 -> f32.
__global__ void k_detect(const unsigned int* __restrict__ q, int* __restrict__ flag) {
    const int lane = threadIdx.x;  // 64 threads
    int cnt = 0;
    for (int i = lane; i < 1024; i += 64) {
        const unsigned int w = q[i];
        const int e = (w >> 7) & 0xFF;
        if (e >= 192 || (e > 0 && e < 64)) cnt++;
    }
    for (int m = 1; m < 64; m <<= 1) cnt += __shfl_xor(cnt, m, 64);
    if (lane == 0) flag[0] = (cnt > 64) ? 1 : 0;
}

__device__ inline void cast_body(const void* src, bf16* dst, int n, int isf32) {
    const int stride = gridDim.x * 256 * 8;
    for (int i = (blockIdx.x * 256 + threadIdx.x) * 8; i < n; i += stride) {
        if (isf32) {
            const float* s = (const float*)src + i;
            float4 a = *(const float4*)(s);
            float4 b = *(const float4*)(s + 4);
            bf16x8 o;
            o[0] = (__bf16)a.x; o[1] = (__bf16)a.y; o[2] = (__bf16)a.z; o[3] = (__bf16)a.w;
            o[4] = (__bf16)b.x; o[5] = (__bf16)b.y; o[6] = (__bf16)b.z; o[7] = (__bf16)b.w;
            *reinterpret_cast<bf16x8*>(dst + i) = o;
        } else {
            *reinterpret_cast<bf16x8*>(dst + i) =
                *reinterpret_cast<const bf16x8*>((const __bf16*)src + i);
        }
    }
}

__global__ __launch_bounds__(256) void k_cast3(
    const void* s0, const void* s1, const void* s2,
    bf16* d0, bf16* d1, bf16* d2, int n, const int* __restrict__ flag) {
    const int t = blockIdx.y;
    const void* s = (t == 0) ? s0 : (t == 1) ? s1 : s2;
    bf16* d = (t == 0) ? d0 : (t == 1) ? d1 : d2;
    cast_body(s, d, n, flag[0]);
}

__global__ __launch_bounds__(256) void k_cast4(
    const void* s0, const void* s1, const void* s2, const void* s3,
    bf16* d0, bf16* d1, bf16* d2, bf16* d3, int n, const int* __restrict__ flag) {
    const int t = blockIdx.y;
    const void* s = (t == 0) ? s0 : (t == 1) ? s1 : (t == 2) ? s2 : s3;
    bf16* d = (t == 0) ? d0 : (t == 1) ? d1 : (t == 2) ? d2 : d3;
    cast_body(s, d, n, flag[0]);
}

// x @ W^T + b. mode 0/1: head-split [H][S][DK]; mode 2: transposed [DM][S];
// mode 3: row-major [S][DM], dtype per flag.   (verified)
__global__ __launch_bounds__(256) void k_proj(
    const bf16* __restrict__ X, const bf16* __restrict__ W,
    const bf16* __restrict__ bias, void* __restrict__ dstv, int mode,
    const int* __restrict__ flag)
{
    const int isf32 = flag[0];
    const int lane = threadIdx.x & 63;
    const int w    = threadIdx.x >> 6;
    const int lr   = lane & 15, lg = lane >> 4;
    const int rbase = blockIdx.x * 64 + w * 16;
    const int nbase = blockIdx.y * 64;

    f32x4 acc[4] = {};
    const bf16* xrow = X + (size_t)(rbase + lr) * DM + lg * 8;
    for (int kk = 0; kk < DM; kk += 32) {
        bf16x8 a = load_frag(xrow + kk);
#pragma unroll
        for (int nt = 0; nt < 4; ++nt) {
            bf16x8 b = load_frag(W + (size_t)(nbase + nt * 16 + lr) * DM + kk + lg * 8);
            acc[nt] = __builtin_amdgcn_mfma_f32_16x16x32_bf16(a, b, acc[nt], 0, 0, 0);
        }
    }
#pragma unroll
    for (int nt = 0; nt < 4; ++nt) {
        const int col = nbase + nt * 16 + lr;
        const float bv = __bfloat162float(bias[col]);
#pragma unroll
        for (int r = 0; r < 4; ++r) {
            const int row = rbase + lg * 4 + r;
            const float v = acc[nt][r] + bv;
            if (mode == 3) {
                const size_t off = (size_t)row * DM + col;
                if (isf32) ((float*)dstv)[off] = v;
                else       ((bf16*)dstv)[off] = __float2bfloat16(v);
            } else {
                size_t off;
                if (mode == 2) off = (size_t)col * S + row;
                else           off = (size_t)(col >> 6) * (S * DK) + (size_t)row * DK + (col & 63);
                ((bf16*)dstv)[off] = __float2bfloat16(v);
            }
        }
    }
}

// Partial row sums of exp(scores/8) over this block's k-half. (verified R5)
__global__ __launch_bounds__(256) void k_rowsum(
    const bf16* __restrict__ qh, const bf16* __restrict__ kh,
    float* __restrict__ rs)
{
    const int lane = threadIdx.x & 63;
    const int w    = threadIdx.x >> 6;
    const int lr   = lane & 15, lg = lane >> 4;
    const int h    = blockIdx.y;
    const int half = blockIdx.z;
    const int q0   = blockIdx.x * 64 + w * 16;

    const bf16* qb = qh + (size_t)h * (S * DK);
    const bf16* kb = kh + (size_t)h * (S * DK);
    const bf16x8 aq0 = load_frag(qb + (size_t)(q0 + lr) * DK + lg * 8);
    const bf16x8 aq1 = load_frag(qb + (size_t)(q0 + lr) * DK + 32 + lg * 8);

    float s = 0.f;
    for (int kp = half * KHALF; kp < half * KHALF + KHALF; kp += 16) {
        bf16x8 b0 = load_frag(kb + (size_t)(kp + lr) * DK + lg * 8);
        bf16x8 b1 = load_frag(kb + (size_t)(kp + lr) * DK + 32 + lg * 8);
        f32x4 d = {};
        d = __builtin_amdgcn_mfma_f32_16x16x32_bf16(b0, aq0, d, 0, 0, 0);
        d = __builtin_amdgcn_mfma_f32_16x16x32_bf16(b1, aq1, d, 0, 0, 0);
        s += __expf(d[0] * 0.125f) + __expf(d[1] * 0.125f) +
             __expf(d[2] * 0.125f) + __expf(d[3] * 0.125f);
    }
    s += __shfl_xor(s, 16, 64);
    s += __shfl_xor(s, 32, 64);
    if (lane < 16)
        rs[(size_t)half * NH * S + (size_t)h * S + q0 + lr] = s;
}

// R7 skeleton with qs=2: each wave owns 32 q-rows (2 subtiles of 16), so each
// K/V load feeds 2 MFMA+exp chains (2x intensity, 2x ILP). Wave-private P in
// LDS [2 qs][16][136] (2-tile staging), flushed per 128-k pair with 512B
// nontemporal segments. No __syncthreads in the main loop (P is wave-private).
__global__ __launch_bounds__(256) void k_attn(
    const bf16* __restrict__ qh, const bf16* __restrict__ kh,
    const bf16* __restrict__ vt, const float* __restrict__ rs,
    void* __restrict__ doutv, bf16* __restrict__ ctxp,
    const int* __restrict__ flag)
{
    __shared__ __align__(16) bf16 Plds[4][2][16][136];
    const int isf32 = flag[0];
    const int lane = threadIdx.x & 63;
    const int w    = threadIdx.x >> 6;
    const int lr   = lane & 15, lg = lane >> 4;
    const int h    = blockIdx.y;
    const int half = blockIdx.z;
    const int q0w  = blockIdx.x * 128 + w * 32;   // wave's 32-q base
    const int k0   = half * KHALF;

    const bf16* qb = qh + (size_t)h * (S * DK);
    const bf16* kb = kh + (size_t)h * (S * DK);
    const bf16* vb = vt + (size_t)h * (S * DK);

    bf16x8 aq[2][2];
    float  inv[2];
#pragma unroll
    for (int qs = 0; qs < 2; ++qs) {
        const int qr = q0w + qs * 16 + lr;
        aq[qs][0] = load_frag(qb + (size_t)qr * DK + lg * 8);
        aq[qs][1] = load_frag(qb + (size_t)qr * DK + 32 + lg * 8);
        inv[qs] = 1.0f / (rs[(size_t)h * S + qr] +
                          rs[(size_t)NH * S + (size_t)h * S + qr]);
    }

    float* poutF = (float*)doutv + (size_t)S * DM + (size_t)h * S * S;
    bf16*  poutB = (bf16*)doutv  + (size_t)S * DM + (size_t)h * S * S;

    // flush mapping: half-wave -> row parity, lane&31 -> 4-col chunk
    const int fr2 = lane >> 5;          // 0..1
    const int fc2 = (lane & 31) * 4;    // 0..124

    f32x4 acc[2][4] = {};
    for (int tp = 0; tp < KHALF / 128; ++tp) {   // 16 iters of 2 tiles
#pragma unroll
        for (int tt = 0; tt < 2; ++tt) {
            const int kt = k0 + tp * 128 + tt * 64;
            const int cb = tt * 64;              // column base in Plds
            // ---- QK^T (swapped: D rows = k, cols = q), exp, stage bf16 ----
#pragma unroll
            for (int sub = 0; sub < 4; ++sub) {
                const int kp = kt + sub * 16;
                bf16x8 b0 = load_frag(kb + (size_t)(kp + lr) * DK + lg * 8);
                bf16x8 b1 = load_frag(kb + (size_t)(kp + lr) * DK + 32 + lg * 8);
#pragma unroll
                for (int qs = 0; qs < 2; ++qs) {
                    f32x4 d = {};
                    d = __builtin_amdgcn_mfma_f32_16x16x32_bf16(b0, aq[qs][0], d, 0, 0, 0);
                    d = __builtin_amdgcn_mfma_f32_16x16x32_bf16(b1, aq[qs][1], d, 0, 0, 0);
                    bf16x4 pv;
                    pv[0] = (__bf16)(__expf(d[0] * 0.125f) * inv[qs]);
                    pv[1] = (__bf16)(__expf(d[1] * 0.125f) * inv[qs]);
                    pv[2] = (__bf16)(__expf(d[2] * 0.125f) * inv[qs]);
                    pv[3] = (__bf16)(__expf(d[3] * 0.125f) * inv[qs]);
                    *reinterpret_cast<bf16x4*>(
                        &Plds[w][qs][lr][cb + sub * 16 + 4 * lg]) = pv;
                }
            }
            // ---- PV on this 64-k tile (V loads shared across qs) ----
            bf16x8 ap[2][2];
#pragma unroll
            for (int qs = 0; qs < 2; ++qs) {
                ap[qs][0] = *reinterpret_cast<const bf16x8*>(&Plds[w][qs][lr][cb + lg * 8]);
                ap[qs][1] = *reinterpret_cast<const bf16x8*>(&Plds[w][qs][lr][cb + 32 + lg * 8]);
            }
#pragma unroll
            for (int dt = 0; dt < 4; ++dt) {
                bf16x8 v0 = load_frag(vb + (size_t)(dt * 16 + lr) * S + kt + lg * 8);
                bf16x8 v1 = load_frag(vb + (size_t)(dt * 16 + lr) * S + kt + 32 + lg * 8);
#pragma unroll
                for (int qs = 0; qs < 2; ++qs) {
                    acc[qs][dt] = __builtin_amdgcn_mfma_f32_16x16x32_bf16(ap[qs][0], v0, acc[qs][dt], 0, 0, 0);
                    acc[qs][dt] = __builtin_amdgcn_mfma_f32_16x16x32_bf16(ap[qs][1], v1, acc[qs][dt], 0, 0, 0);
                }
            }
        }
        // ---- flush 2 tiles: 32 rows x 128 cols ----
        const int ktbase = k0 + tp * 128;
        if (isf32) {
#pragma unroll
            for (int j = 0; j < 16; ++j) {
                const int row = 2 * j + fr2;           // 0..31
                const int qs = row >> 4, rr = row & 15;
                bf16x4 x = *reinterpret_cast<const bf16x4*>(&Plds[w][qs][rr][fc2]);
                f32x4 o;
                o[0] = (float)x[0]; o[1] = (float)x[1];
                o[2] = (float)x[2]; o[3] = (float)x[3];
                __builtin_nontemporal_store(
                    o, reinterpret_cast<f32x4*>(
                           poutF + (size_t)(q0w + row) * S + ktbase + fc2));
            }
        } else {
#pragma unroll
            for (int j = 0; j < 16; ++j) {
                const int row = 2 * j + fr2;
                const int qs = row >> 4, rr = row & 15;
                bf16x4 x = *reinterpret_cast<const bf16x4*>(&Plds[w][qs][rr][fc2]);
                *reinterpret_cast<bf16x4*>(
                    poutB + (size_t)(q0w + row) * S + ktbase + fc2) = x;
            }
        }
    }
    bf16* cp = ctxp + (size_t)half * S * DM;
#pragma unroll
    for (int qs = 0; qs < 2; ++qs)
#pragma unroll
        for (int dt = 0; dt < 4; ++dt)
#pragma unroll
            for (int r = 0; r < 4; ++r)
                cp[(size_t)(q0w + qs * 16 + 4 * lg + r) * DM + h * DK + dt * 16 + lr] =
                    __float2bfloat16(acc[qs][dt][r]);
}

// ctx = ctxp[0] + ctxp[1] (bf16)
__global__ __launch_bounds__(256) void k_reduce(const bf16* __restrict__ ctxp,
                                               bf16* __restrict__ ctx) {
    const int i = (blockIdx.x * 256 + threadIdx.x) * 8;
    bf16x8 a = *reinterpret_cast<const bf16x8*>(ctxp + i);
    bf16x8 b = *reinterpret_cast<const bf16x8*>(ctxp + (size_t)S * DM + i);
    bf16x8 o;
#pragma unroll
    for (int j = 0; j < 8; ++j) o[j] = (__bf16)((float)a[j] + (float)b[j]);
    *reinterpret_cast<bf16x8*>(ctx + i) = o;
}

extern "C" void kernel_launch(void* const* d_in, const int* in_sizes, int n_in,
                              void* d_out, int out_size, void* d_ws, size_t ws_size,
                              hipStream_t stream) {
    char* wsb = (char*)d_ws;
    int*   flag = (int*)wsb;                                   // 16 B
    float* rs   = (float*)(wsb + 16);                          // 2*NH*S f32
    bf16*  conv = (bf16*)(wsb + 16 + (size_t)2 * NH * S * 4);

    const size_t nQ = (size_t)S * DM, nW = (size_t)DM * DM, nB = DM;
    bf16* Qc  = conv;
    bf16* Kc  = Qc + nQ;
    bf16* Vc  = Kc + nQ;
    bf16* Wqc = Vc + nQ;
    bf16* Wkc = Wqc + nW;
    bf16* Wvc = Wkc + nW;
    bf16* Woc = Wvc + nW;
    bf16* bqc = Woc + nW;
    bf16* bkc = bqc + nB;
    bf16* bvc = bkc + nB;
    bf16* boc = bvc + nB;
    bf16* qh  = boc + nB;
    bf16* kh  = qh + nQ;
    bf16* vt  = kh + nQ;
    // aliases (Qc/Kc/Vc dead after projections):
    bf16* ctxp = Qc;   // 2*nQ bf16 partial ctx
    bf16* ctx  = Vc;   // nQ bf16 summed ctx

    const size_t need = (size_t)((char*)(vt + nQ) - wsb);
    if (ws_size < need) return;

    dim3 blk(256);
    k_detect<<<1, 64, 0, stream>>>((const unsigned int*)d_in[0], flag);

    k_cast3<<<dim3((int)(nQ / 2048), 3), blk, 0, stream>>>(
        d_in[0], d_in[1], d_in[2], Qc, Kc, Vc, (int)nQ, flag);
    k_cast4<<<dim3((int)(nW / 2048), 4), blk, 0, stream>>>(
        d_in[3], d_in[5], d_in[7], d_in[9], Wqc, Wkc, Wvc, Woc, (int)nW, flag);
    k_cast4<<<dim3(1, 4), blk, 0, stream>>>(
        d_in[4], d_in[6], d_in[8], d_in[10], bqc, bkc, bvc, boc, (int)nB, flag);

    k_proj<<<dim3(S / 64, DM / 64), blk, 0, stream>>>(Qc, Wqc, bqc, qh, 0, flag);
    k_proj<<<dim3(S / 64, DM / 64), blk, 0, stream>>>(Kc, Wkc, bkc, kh, 1, flag);
    k_proj<<<dim3(S / 64, DM / 64), blk, 0, stream>>>(Vc, Wvc, bvc, vt, 2, flag);
    k_rowsum<<<dim3(S / 64, NH, KSPLIT), blk, 0, stream>>>(qh, kh, rs);
    k_attn<<<dim3(S / 128, NH, KSPLIT), blk, 0, stream>>>(qh, kh, vt, rs, d_out, ctxp, flag);
    k_reduce<<<dim3((int)(nQ / 8 / 256)), blk, 0, stream>>>(ctxp, ctx);
    k_proj<<<dim3(S / 64, DM / 64), blk, 0, stream>>>(ctx, Woc, boc, d_out, 3, flag);
}

// Round 9
// 469.382 us; speedup vs baseline: 1.7030x; 1.3408x over previous
//
#include <hip/hip_runtime.h>
#include <hip/hip_bf16.h>

#define S 4096
#define DM 768
#define NH 12
#define DK 64
#define KSPLIT 2
#define KHALF (S / KSPLIT)
#define RPARTS 8
#define RCHUNK (S / RPARTS)

typedef __bf16 bf16x8 __attribute__((ext_vector_type(8)));
typedef __bf16 bf16x4 __attribute__((ext_vector_type(4)));
typedef float f32x4 __attribute__((ext_vector_type(4)));
using bf16 = __hip_bfloat16;

__device__ inline bf16x8 load_frag(const bf16* p) {
    return *reinterpret_cast<const bf16x8*>(p);
}

// Detect input dtype (f32 vs bf16) from bit patterns; flag=1 -> f32.
__global__ void k_detect(const unsigned int* __restrict__ q, int* __restrict__ flag) {
    const int lane = threadIdx.x;  // 64 threads
    int cnt = 0;
    for (int i = lane; i < 1024; i += 64) {
        const unsigned int w = q[i];
        const int e = (w >> 7) & 0xFF;
        if (e >= 192 || (e > 0 && e < 64)) cnt++;
    }
    for (int m = 1; m < 64; m <<= 1) cnt += __shfl_xor(cnt, m, 64);
    if (lane == 0) flag[0] = (cnt > 64) ? 1 : 0;
}

__device__ inline void cast_body(const void* src, bf16* dst, int n, int isf32) {
    const int stride = gridDim.x * 256 * 8;
    for (int i = (blockIdx.x * 256 + threadIdx.x) * 8; i < n; i += stride) {
        if (isf32) {
            const float* s = (const float*)src + i;
            float4 a = *(const float4*)(s);
            float4 b = *(const float4*)(s + 4);
            bf16x8 o;
            o[0] = (__bf16)a.x; o[1] = (__bf16)a.y; o[2] = (__bf16)a.z; o[3] = (__bf16)a.w;
            o[4] = (__bf16)b.x; o[5] = (__bf16)b.y; o[6] = (__bf16)b.z; o[7] = (__bf16)b.w;
            *reinterpret_cast<bf16x8*>(dst + i) = o;
        } else {
            *reinterpret_cast<bf16x8*>(dst + i) =
                *reinterpret_cast<const bf16x8*>((const __bf16*)src + i);
        }
    }
}

__global__ __launch_bounds__(256) void k_cast3(
    const void* s0, const void* s1, const void* s2,
    bf16* d0, bf16* d1, bf16* d2, int n, const int* __restrict__ flag) {
    const int t = blockIdx.y;
    const void* s = (t == 0) ? s0 : (t == 1) ? s1 : s2;
    bf16* d = (t == 0) ? d0 : (t == 1) ? d1 : d2;
    cast_body(s, d, n, flag[0]);
}

__global__ __launch_bounds__(256) void k_cast4(
    const void* s0, const void* s1, const void* s2, const void* s3,
    bf16* d0, bf16* d1, bf16* d2, bf16* d3, int n, const int* __restrict__ flag) {
    const int t = blockIdx.y;
    const void* s = (t == 0) ? s0 : (t == 1) ? s1 : (t == 2) ? s2 : s3;
    bf16* d = (t == 0) ? d0 : (t == 1) ? d1 : (t == 2) ? d2 : d3;
    cast_body(s, d, n, flag[0]);
}

// x @ W^T + b. mode 0/1: head-split [H][S][DK]; mode 2: transposed [DM][S];
// mode 3: row-major [S][DM], dtype per flag.   (verified)
__global__ __launch_bounds__(256) void k_proj(
    const bf16* __restrict__ X, const bf16* __restrict__ W,
    const bf16* __restrict__ bias, void* __restrict__ dstv, int mode,
    const int* __restrict__ flag)
{
    const int isf32 = flag[0];
    const int lane = threadIdx.x & 63;
    const int w    = threadIdx.x >> 6;
    const int lr   = lane & 15, lg = lane >> 4;
    const int rbase = blockIdx.x * 64 + w * 16;
    const int nbase = blockIdx.y * 64;

    f32x4 acc[4] = {};
    const bf16* xrow = X + (size_t)(rbase + lr) * DM + lg * 8;
    for (int kk = 0; kk < DM; kk += 32) {
        bf16x8 a = load_frag(xrow + kk);
#pragma unroll
        for (int nt = 0; nt < 4; ++nt) {
            bf16x8 b = load_frag(W + (size_t)(nbase + nt * 16 + lr) * DM + kk + lg * 8);
            acc[nt] = __builtin_amdgcn_mfma_f32_16x16x32_bf16(a, b, acc[nt], 0, 0, 0);
        }
    }
#pragma unroll
    for (int nt = 0; nt < 4; ++nt) {
        const int col = nbase + nt * 16 + lr;
        const float bv = __bfloat162float(bias[col]);
#pragma unroll
        for (int r = 0; r < 4; ++r) {
            const int row = rbase + lg * 4 + r;
            const float v = acc[nt][r] + bv;
            if (mode == 3) {
                const size_t off = (size_t)row * DM + col;
                if (isf32) ((float*)dstv)[off] = v;
                else       ((bf16*)dstv)[off] = __float2bfloat16(v);
            } else {
                size_t off;
                if (mode == 2) off = (size_t)col * S + row;
                else           off = (size_t)(col >> 6) * (S * DK) + (size_t)row * DK + (col & 63);
                ((bf16*)dstv)[off] = __float2bfloat16(v);
            }
        }
    }
}

// Partial row sums of exp(scores/8). Each wave: 64 q-rows (4x K-load reuse),
// k-range = RCHUNK per part. rs[part][h][q].  (verbatim from R5, verified)
__global__ __launch_bounds__(256) void k_rowsum(
    const bf16* __restrict__ qh, const bf16* __restrict__ kh,
    float* __restrict__ rs)
{
    const int lane = threadIdx.x & 63;
    const int w    = threadIdx.x >> 6;
    const int lr   = lane & 15;
    const int lg   = lane >> 4;
    const int h    = blockIdx.y;
    const int part = blockIdx.z;
    const int qw   = blockIdx.x * 256 + w * 64;

    const bf16* qb = qh + (size_t)h * (S * DK);
    const bf16* kb = kh + (size_t)h * (S * DK);
    bf16x8 aq[4][2];
#pragma unroll
    for (int qs = 0; qs < 4; ++qs) {
        aq[qs][0] = load_frag(qb + (size_t)(qw + qs * 16 + lr) * DK + lg * 8);
        aq[qs][1] = load_frag(qb + (size_t)(qw + qs * 16 + lr) * DK + 32 + lg * 8);
    }

    float s[4] = {0.f, 0.f, 0.f, 0.f};
    for (int kp = part * RCHUNK; kp < part * RCHUNK + RCHUNK; kp += 16) {
        bf16x8 b0 = load_frag(kb + (size_t)(kp + lr) * DK + lg * 8);
        bf16x8 b1 = load_frag(kb + (size_t)(kp + lr) * DK + 32 + lg * 8);
#pragma unroll
        for (int qs = 0; qs < 4; ++qs) {
            f32x4 d = {};
            d = __builtin_amdgcn_mfma_f32_16x16x32_bf16(b0, aq[qs][0], d, 0, 0, 0);
            d = __builtin_amdgcn_mfma_f32_16x16x32_bf16(b1, aq[qs][1], d, 0, 0, 0);
            s[qs] += __expf(d[0] * 0.125f) + __expf(d[1] * 0.125f) +
                     __expf(d[2] * 0.125f) + __expf(d[3] * 0.125f);
        }
    }
#pragma unroll
    for (int qs = 0; qs < 4; ++qs) {
        float v = s[qs];
        v += __shfl_xor(v, 16, 64);
        v += __shfl_xor(v, 32, 64);
        if (lg == 0)
            rs[((size_t)part * NH + h) * S + qw + qs * 16 + lr] = v;
    }
}

// R8-verified skeleton (qs=2, wave-private 32 q-rows, 2-tile LDS staging,
// 512B nontemporal flush, no main-loop barrier) + V-prefetch: V loads for each
// 64-k tile are issued BEFORE the QK^T/exp/stage phase so their latency hides
// under compute. rs is summed over 8 parts (R5-verified pattern).
__global__ __launch_bounds__(256) void k_attn(
    const bf16* __restrict__ qh, const bf16* __restrict__ kh,
    const bf16* __restrict__ vt, const float* __restrict__ rs,
    void* __restrict__ doutv, bf16* __restrict__ ctxp,
    const int* __restrict__ flag)
{
    __shared__ __align__(16) bf16 Plds[4][2][16][136];
    const int isf32 = flag[0];
    const int lane = threadIdx.x & 63;
    const int w    = threadIdx.x >> 6;
    const int lr   = lane & 15, lg = lane >> 4;
    const int h    = blockIdx.y;
    const int half = blockIdx.z;
    const int q0w  = blockIdx.x * 128 + w * 32;   // wave's 32-q base
    const int k0   = half * KHALF;

    const bf16* qb = qh + (size_t)h * (S * DK);
    const bf16* kb = kh + (size_t)h * (S * DK);
    const bf16* vb = vt + (size_t)h * (S * DK);

    bf16x8 aq[2][2];
    float  inv[2];
#pragma unroll
    for (int qs = 0; qs < 2; ++qs) {
        const int qr = q0w + qs * 16 + lr;
        aq[qs][0] = load_frag(qb + (size_t)qr * DK + lg * 8);
        aq[qs][1] = load_frag(qb + (size_t)qr * DK + 32 + lg * 8);
        float ssum = 0.f;
#pragma unroll
        for (int p = 0; p < RPARTS; ++p)
            ssum += rs[((size_t)p * NH + h) * S + qr];
        inv[qs] = 1.0f / ssum;
    }

    float* poutF = (float*)doutv + (size_t)S * DM + (size_t)h * S * S;
    bf16*  poutB = (bf16*)doutv  + (size_t)S * DM + (size_t)h * S * S;

    // flush mapping: half-wave -> row parity, lane&31 -> 4-col chunk
    const int fr2 = lane >> 5;          // 0..1
    const int fc2 = (lane & 31) * 4;    // 0..124

    f32x4 acc[2][4] = {};
    for (int tp = 0; tp < KHALF / 128; ++tp) {   // 16 iters of 2 tiles
#pragma unroll
        for (int tt = 0; tt < 2; ++tt) {
            const int kt = k0 + tp * 128 + tt * 64;
            const int cb = tt * 64;              // column base in Plds
            // ---- V prefetch for this tile (independent of P) ----
            bf16x8 vv[4][2];
#pragma unroll
            for (int dt = 0; dt < 4; ++dt) {
                vv[dt][0] = load_frag(vb + (size_t)(dt * 16 + lr) * S + kt + lg * 8);
                vv[dt][1] = load_frag(vb + (size_t)(dt * 16 + lr) * S + kt + 32 + lg * 8);
            }
            // ---- QK^T (swapped: D rows = k, cols = q), exp, stage bf16 ----
#pragma unroll
            for (int sub = 0; sub < 4; ++sub) {
                const int kp = kt + sub * 16;
                bf16x8 b0 = load_frag(kb + (size_t)(kp + lr) * DK + lg * 8);
                bf16x8 b1 = load_frag(kb + (size_t)(kp + lr) * DK + 32 + lg * 8);
#pragma unroll
                for (int qs = 0; qs < 2; ++qs) {
                    f32x4 d = {};
                    d = __builtin_amdgcn_mfma_f32_16x16x32_bf16(b0, aq[qs][0], d, 0, 0, 0);
                    d = __builtin_amdgcn_mfma_f32_16x16x32_bf16(b1, aq[qs][1], d, 0, 0, 0);
                    bf16x4 pv;
                    pv[0] = (__bf16)(__expf(d[0] * 0.125f) * inv[qs]);
                    pv[1] = (__bf16)(__expf(d[1] * 0.125f) * inv[qs]);
                    pv[2] = (__bf16)(__expf(d[2] * 0.125f) * inv[qs]);
                    pv[3] = (__bf16)(__expf(d[3] * 0.125f) * inv[qs]);
                    *reinterpret_cast<bf16x4*>(
                        &Plds[w][qs][lr][cb + sub * 16 + 4 * lg]) = pv;
                }
            }
            // ---- PV on this 64-k tile (prefetched V, shared across qs) ----
            bf16x8 ap[2][2];
#pragma unroll
            for (int qs = 0; qs < 2; ++qs) {
                ap[qs][0] = *reinterpret_cast<const bf16x8*>(&Plds[w][qs][lr][cb + lg * 8]);
                ap[qs][1] = *reinterpret_cast<const bf16x8*>(&Plds[w][qs][lr][cb + 32 + lg * 8]);
            }
#pragma unroll
            for (int dt = 0; dt < 4; ++dt) {
#pragma unroll
                for (int qs = 0; qs < 2; ++qs) {
                    acc[qs][dt] = __builtin_amdgcn_mfma_f32_16x16x32_bf16(ap[qs][0], vv[dt][0], acc[qs][dt], 0, 0, 0);
                    acc[qs][dt] = __builtin_amdgcn_mfma_f32_16x16x32_bf16(ap[qs][1], vv[dt][1], acc[qs][dt], 0, 0, 0);
                }
            }
        }
        // ---- flush 2 tiles: 32 rows x 128 cols ----
        const int ktbase = k0 + tp * 128;
        if (isf32) {
#pragma unroll
            for (int j = 0; j < 16; ++j) {
                const int row = 2 * j + fr2;           // 0..31
                const int qs = row >> 4, rr = row & 15;
                bf16x4 x = *reinterpret_cast<const bf16x4*>(&Plds[w][qs][rr][fc2]);
                f32x4 o;
                o[0] = (float)x[0]; o[1] = (float)x[1];
                o[2] = (float)x[2]; o[3] = (float)x[3];
                __builtin_nontemporal_store(
                    o, reinterpret_cast<f32x4*>(
                           poutF + (size_t)(q0w + row) * S + ktbase + fc2));
            }
        } else {
#pragma unroll
            for (int j = 0; j < 16; ++j) {
                const int row = 2 * j + fr2;
                const int qs = row >> 4, rr = row & 15;
                bf16x4 x = *reinterpret_cast<const bf16x4*>(&Plds[w][qs][rr][fc2]);
                *reinterpret_cast<bf16x4*>(
                    poutB + (size_t)(q0w + row) * S + ktbase + fc2) = x;
            }
        }
    }
    bf16* cp = ctxp + (size_t)half * S * DM;
#pragma unroll
    for (int qs = 0; qs < 2; ++qs)
#pragma unroll
        for (int dt = 0; dt < 4; ++dt)
#pragma unroll
            for (int r = 0; r < 4; ++r)
                cp[(size_t)(q0w + qs * 16 + 4 * lg + r) * DM + h * DK + dt * 16 + lr] =
                    __float2bfloat16(acc[qs][dt][r]);
}

// ctx = ctxp[0] + ctxp[1] (bf16)
__global__ __launch_bounds__(256) void k_reduce(const bf16* __restrict__ ctxp,
                                               bf16* __restrict__ ctx) {
    const int i = (blockIdx.x * 256 + threadIdx.x) * 8;
    bf16x8 a = *reinterpret_cast<const bf16x8*>(ctxp + i);
    bf16x8 b = *reinterpret_cast<const bf16x8*>(ctxp + (size_t)S * DM + i);
    bf16x8 o;
#pragma unroll
    for (int j = 0; j < 8; ++j) o[j] = (__bf16)((float)a[j] + (float)b[j]);
    *reinterpret_cast<bf16x8*>(ctx + i) = o;
}

extern "C" void kernel_launch(void* const* d_in, const int* in_sizes, int n_in,
                              void* d_out, int out_size, void* d_ws, size_t ws_size,
                              hipStream_t stream) {
    char* wsb = (char*)d_ws;
    int*   flag = (int*)wsb;                                    // 16 B
    float* rs   = (float*)(wsb + 16);                           // RPARTS*NH*S f32
    bf16*  conv = (bf16*)(wsb + 16 + (size_t)RPARTS * NH * S * 4);

    const size_t nQ = (size_t)S * DM, nW = (size_t)DM * DM, nB = DM;
    bf16* Qc  = conv;
    bf16* Kc  = Qc + nQ;
    bf16* Vc  = Kc + nQ;
    bf16* Wqc = Vc + nQ;
    bf16* Wkc = Wqc + nW;
    bf16* Wvc = Wkc + nW;
    bf16* Woc = Wvc + nW;
    bf16* bqc = Woc + nW;
    bf16* bkc = bqc + nB;
    bf16* bvc = bkc + nB;
    bf16* boc = bvc + nB;
    bf16* qh  = boc + nB;
    bf16* kh  = qh + nQ;
    bf16* vt  = kh + nQ;
    // aliases (Qc/Kc/Vc dead after projections):
    bf16* ctxp = Qc;   // 2*nQ bf16 partial ctx
    bf16* ctx  = Vc;   // nQ bf16 summed ctx

    const size_t need = (size_t)((char*)(vt + nQ) - wsb);
    if (ws_size < need) return;

    dim3 blk(256);
    k_detect<<<1, 64, 0, stream>>>((const unsigned int*)d_in[0], flag);

    k_cast3<<<dim3((int)(nQ / 2048), 3), blk, 0, stream>>>(
        d_in[0], d_in[1], d_in[2], Qc, Kc, Vc, (int)nQ, flag);
    k_cast4<<<dim3((int)(nW / 2048), 4), blk, 0, stream>>>(
        d_in[3], d_in[5], d_in[7], d_in[9], Wqc, Wkc, Wvc, Woc, (int)nW, flag);
    k_cast4<<<dim3(1, 4), blk, 0, stream>>>(
        d_in[4], d_in[6], d_in[8], d_in[10], bqc, bkc, bvc, boc, (int)nB, flag);

    k_proj<<<dim3(S / 64, DM / 64), blk, 0, stream>>>(Qc, Wqc, bqc, qh, 0, flag);
    k_proj<<<dim3(S / 64, DM / 64), blk, 0, stream>>>(Kc, Wkc, bkc, kh, 1, flag);
    k_proj<<<dim3(S / 64, DM / 64), blk, 0, stream>>>(Vc, Wvc, bvc, vt, 2, flag);
    k_rowsum<<<dim3(S / 256, NH, RPARTS), blk, 0, stream>>>(qh, kh, rs);
    k_attn<<<dim3(S / 128, NH, KSPLIT), blk, 0, stream>>>(qh, kh, vt, rs, d_out, ctxp, flag);
    k_reduce<<<dim3((int)(nQ / 8 / 256)), blk, 0, stream>>>(ctxp, ctx);
    k_proj<<<dim3(S / 64, DM / 64), blk, 0, stream>>>(ctx, Woc, boc, d_out, 3, flag);
}